// Round 14
// baseline (211.043 us; speedup 1.0000x reference)
//
#include <hip/hip_runtime.h>
#include <math.h>

#define BATCH 2048
#define NN 64
#define FEAT 40
#define M 10
#define NPAIR 32      // 64 rows as 32 float2 row-pairs
#define PPAD 38       // ring prefetch touches pair index up to p+6 = 36; pad

__device__ __forceinline__ float rl(float v, int l) {   // readlane (uniform l)
    return __int_as_float(__builtin_amdgcn_readlane(__float_as_int(v), l));
}
__device__ __forceinline__ int rli(int v, int l) {
    return __builtin_amdgcn_readlane(v, l);
}
__device__ __forceinline__ float wsum(float v) {
#pragma unroll
    for (int o = 32; o >= 1; o >>= 1) v += __shfl_xor(v, o, 64);
    return v;
}

// One wave per batch element; fused rank-2 LDL^T + forward solves (R13).
// R14: (a) float2-interleaved matrix: row-pair per lane -> the Schur stream
// is 1 ds_read_b64 + 1 ds_write_b64 per pair (halves LDS ops vs 2+2 b32);
// (b) depth-4 ring prefetch: 5 pair reads issue before the pivot chain +
// 22-fma z-update (~150 cyc of independent work) -> ~120cyc LDS latency
// buried; (c) plain fmaf (no inline-asm pk_fma: constraint-induced copies).
__global__ __launch_bounds__(64)
__attribute__((amdgpu_waves_per_eu(2, 2)))
void muygps_kernel(
    const float* __restrict__ x,      // (20000, 40)
    const float* __restrict__ ls,     // (10,)
    const float* __restrict__ epsv,   // (10,)
    const int*   __restrict__ bidx,   // (2048,)
    const int*   __restrict__ nidx,   // (2048, 64)
    const float* __restrict__ tgt,    // (2048, 64, 10)
    float* __restrict__ out,          // pred | var | sigma
    float* __restrict__ ws)           // (M, BATCH) sigma contributions
{
    __shared__ float2 Ap[PPAD * NN];  // pair p, lane: {A[2p][lane], A[2p+1][lane]}
    __shared__ float rvb[NN];         // 1/D[k]

    const int b    = blockIdx.x;
    const int lane = threadIdx.x;

    // ---- lane's neighbor row -> 40 statically-indexed VGPRs ----
    const int nv = nidx[b * NN + lane];
    const float* xr0 = x + (size_t)nv * FEAT;
    float xc[FEAT];
#pragma unroll
    for (int q = 0; q < FEAT / 4; ++q) {
        const float4 v = *(const float4*)(xr0 + 4 * q);
        xc[4*q] = v.x; xc[4*q+1] = v.y; xc[4*q+2] = v.z; xc[4*q+3] = v.w;
    }
    float nl = 0.f;
#pragma unroll
    for (int f = 0; f < FEAT; ++f) nl = fmaf(xc[f], xc[f], nl);

    // ---- crosswise distance (batch row via uniform loads) ----
    const float* xbp = x + (size_t)bidx[b] * FEAT;
    float gc = 0.f, nb = 0.f;
#pragma unroll
    for (int f = 0; f < FEAT; ++f) {
        const float bf = xbp[f];
        gc = fmaf(bf, xc[f], gc);     // identical chains -> exact cancel on dup
        nb = fmaf(bf, bf, nb);
    }
    float cd2 = (nb + nl) - 2.f * gc;
    cd2 = (cd2 < 0.05f) ? 0.f : cd2;  // legit d2 ~ 80 in 40-D N(0,1) data
    const float cdv = sqrtf(cd2);

    unsigned done = 0;
    const unsigned all = (1u << M) - 1u;
    while (true) {
        const int   lead = __ffs(~done) - 1;     // wave-uniform
        const float lls  = ls[lead];
        const float lep  = epsv[lead];
        const float il   = -1.0f / lls;

        // ---- Gram + kernel transform, 2 rows/iter, unroll 2 ----
#pragma unroll 2
        for (int i = 0; i < NN; i += 2) {
            const int ri0 = rli(nv, i), ri1 = rli(nv, i + 1);
            const float* r0 = x + (size_t)ri0 * FEAT;   // uniform -> s_loads
            const float* r1 = x + (size_t)ri1 * FEAT;
            float g0 = 0.f, g1 = 0.f;
#pragma unroll
            for (int f = 0; f < FEAT; ++f) {
                g0 = fmaf(r0[f], xc[f], g0);
                g1 = fmaf(r1[f], xc[f], g1);
            }
            float d2a = (rl(g0, i) + nl) - 2.f * g0;    // Gram diag = |x_i|^2
            float d2b = (rl(g1, i + 1) + nl) - 2.f * g1;
            d2a = (d2a < 0.05f) ? 0.f : d2a;
            d2b = (d2b < 0.05f) ? 0.f : d2b;
            float va = __expf(sqrtf(d2a) * il);
            float vb = __expf(sqrtf(d2b) * il);
            if (lane == i)     va += lep;
            if (lane == i + 1) vb += lep;
            Ap[(i >> 1) * NN + lane] = float2{va, vb};  // ds_write_b64
        }
        const float kcv = __expf(cdv * il);

        // ---- RHS registers: z[0]=Kc, z[1..10]=targets ----
        float z[M + 1];
        z[0] = kcv;
        {
            const float* trow = tgt + ((size_t)b * NN + lane) * M;
#pragma unroll
            for (int q = 0; q < M / 2; ++q) {
                const float2 v = *(const float2*)(trow + 2 * q);
                z[2 * q + 1] = v.x; z[2 * q + 2] = v.y;
            }
        }

        // ---- fused rank-2 LDL^T + forward solves, float2 stream ----
        float2 pv = Ap[lane];             // pair 0 -> pivot rows 0,1
        float pc0 = pv.x, pc1 = pv.y;
        float2 nv2 = Ap[NN + lane];       // pair 1 -> next pivots
        float n2 = nv2.x, n3 = nv2.y;
        for (int p = 0; p < 31; ++p) {
            const int k = 2 * p;
            // issue all pair reads up front (latency buried under chain below)
            float2 V = Ap[(p + 2) * NN + lane];          // capture pair
            float2 P[4];                                  // ring: pairs p+3..p+6
            P[0] = Ap[(p + 3) * NN + lane];
            P[1] = Ap[(p + 4) * NN + lane];
            P[2] = Ap[(p + 5) * NN + lane];
            P[3] = Ap[(p + 6) * NN + lane];
            // pivot chain (register-only)
            const float d0  = rl(pc0, k);
            const float r0  = __builtin_amdgcn_rcpf(d0);
            const float cv0 = pc0 * (-r0);
            pc1 = fmaf(cv0, rl(pc0, k + 1), pc1);
            const float d1  = rl(pc1, k + 1);
            const float r1  = __builtin_amdgcn_rcpf(d1);
            const float cv1 = pc1 * (-r1);
            rvb[k]     = r0;
            rvb[k + 1] = r1;
            // fused solve updates for columns k, k+1
            const float lv0 = (lane > k)     ? cv0 : 0.f;
            const float lv1 = (lane > k + 1) ? cv1 : 0.f;
#pragma unroll
            for (int j = 0; j < M + 1; ++j) {
                z[j] = fmaf(lv0, rl(z[j], k), z[j]);
                z[j] = fmaf(lv1, rl(z[j], k + 1), z[j]);
            }
            // peel pair p+1 (registers) -> next pivots
            const float t2 = fmaf(cv1, rl(pc1, k + 2), fmaf(cv0, rl(pc0, k + 2), n2));
            const float t3 = fmaf(cv1, rl(pc1, k + 3), fmaf(cv0, rl(pc0, k + 3), n3));
            // capture pair p+2 in registers (never re-stored)
            n2 = fmaf(cv1, rl(pc1, k + 4), fmaf(cv0, rl(pc0, k + 4), V.x));
            n3 = fmaf(cv1, rl(pc1, k + 5), fmaf(cv0, rl(pc0, k + 5), V.y));
            // stream pairs p+3..31: ring-prefetched read/update/write
            const int rem = NPAIR - (p + 3);             // 29-p
#pragma unroll 4
            for (int t = 0; t < rem; ++t) {
                const int q = p + 3 + t;
                float2 cur = P[t & 3];
                P[t & 3] = Ap[(q + 4) * NN + lane];      // prefetch (pad-safe)
                const int i0 = 2 * q;
                cur.x = fmaf(cv0, rl(pc0, i0),     fmaf(cv1, rl(pc1, i0),     cur.x));
                cur.y = fmaf(cv0, rl(pc0, i0 + 1), fmaf(cv1, rl(pc1, i0 + 1), cur.y));
                Ap[q * NN + lane] = cur;                 // ds_write_b64
            }
            pc0 = t2; pc1 = t3;
        }
        {   // final step k=62 (rows 62,63 in pc0,pc1)
            const float d0  = rl(pc0, 62);
            const float r0  = __builtin_amdgcn_rcpf(d0);
            const float cv0 = pc0 * (-r0);
            pc1 = fmaf(cv0, rl(pc0, 63), pc1);
            const float d1  = rl(pc1, 63);
            const float r1  = __builtin_amdgcn_rcpf(d1);
            rvb[62] = r0;
            rvb[63] = r1;
            const float lv0 = (lane > 62) ? cv0 : 0.f;   // col 63 affects nobody
#pragma unroll
            for (int j = 0; j < M + 1; ++j)
                z[j] = fmaf(lv0, rl(z[j], 62), z[j]);
        }

        // ---- quadratic forms with D^-1; lane-parallel output stores ----
        const float rvv = rvb[lane];
        const float zc  = z[0];
        const float quad = wsum(zc * zc * rvv);
        unsigned mb = 0;
#pragma unroll
        for (int m = 0; m < M; ++m)
            if (!(done & (1u << m)) && ls[m] == lls && epsv[m] == lep)
                mb |= 1u << m;
        float predv = 0.f, sigv = 0.f;
#pragma unroll
        for (int m = 0; m < M; ++m) {
            if (mb & (1u << m)) {
                const float zm = z[m + 1];
                const float pm = wsum(zc * zm * rvv);
                const float sm = wsum(zm * zm * rvv);
                if (lane == m) { predv = pm; sigv = sm; }
            }
        }
        if (lane < M && ((mb >> lane) & 1u)) {
            out[b * M + lane] = predv;
            out[BATCH * M + b * M + lane] = 1.0f - quad;
            ws[lane * BATCH + b] = sigv;
        }
        done |= mb;
        if (done == all) break;
    }
}

// 1 block x 640: wave w reduces model w's 2048 contributions.
__global__ __launch_bounds__(640)
void sigma_reduce(const float* __restrict__ ws, float* __restrict__ out) {
    const int w = threadIdx.x >> 6, lane = threadIdx.x & 63;
    const float4* p = (const float4*)(ws + w * BATCH);
    float a = 0.f;
#pragma unroll
    for (int i = 0; i < BATCH / 4 / 64; ++i) {
        const float4 v = p[i * 64 + lane];
        a += (v.x + v.y) + (v.z + v.w);
    }
    a = wsum(a);
    if (lane == 0)
        out[2 * BATCH * M + w] = a * (1.0f / (float)(BATCH * NN));
}

extern "C" void kernel_launch(void* const* d_in, const int* in_sizes, int n_in,
                              void* d_out, int out_size, void* d_ws, size_t ws_size,
                              hipStream_t stream) {
    const float* x   = (const float*)d_in[0];
    const float* lsp = (const float*)d_in[1];
    const float* ep  = (const float*)d_in[2];
    const int*   bi  = (const int*)d_in[3];
    const int*   ni  = (const int*)d_in[4];
    const float* tg  = (const float*)d_in[5];
    float* out = (float*)d_out;
    float* ws  = (float*)d_ws;        // M*BATCH*4 = 80 KB

    muygps_kernel<<<BATCH, 64, 0, stream>>>(x, lsp, ep, bi, ni, tg, out, ws);
    sigma_reduce<<<1, 640, 0, stream>>>(ws, out);
}

// Round 15
// 141.866 us; speedup vs baseline: 1.4876x; 1.4876x over previous
//
#include <hip/hip_runtime.h>
#include <math.h>

#define BATCH 2048
#define NN 64
#define FEAT 40
#define M 10
#define NPAIR 32      // 64 rows stored as 32 float2 row-pairs (interleaved)
#define PPAD 34       // reads touch pair index up to 33 (pad; values unused)

__device__ __forceinline__ float rl(float v, int l) {   // readlane (uniform l)
    return __int_as_float(__builtin_amdgcn_readlane(__float_as_int(v), l));
}
__device__ __forceinline__ int rli(int v, int l) {
    return __builtin_amdgcn_readlane(v, l);
}
__device__ __forceinline__ float wsum(float v) {
#pragma unroll
    for (int o = 32; o >= 1; o >>= 1) v += __shfl_xor(v, o, 64);
    return v;
}

// One wave per batch element; fused rank-2 LDL^T + forward solves (R13).
// R15 = R13 + (a) float2 row-pair LDS layout: stream iter = 1 ds_read_b64 +
// 1 ds_write_b64 (halves LDS instr vs b32); STATIC prefetch regs only
// (R14's ring P[t&3] was dynamic reg indexing -> scratch spill, WRITE_SIZE
// 896KB->5MB, 2x regression); (b) rvb[] LDS array replaced by per-lane
// cndmask latch of 1/D[lane] (removes 62 same-addr ds_writes + final read).
__global__ __launch_bounds__(64)
__attribute__((amdgpu_waves_per_eu(2, 2)))
void muygps_kernel(
    const float* __restrict__ x,      // (20000, 40)
    const float* __restrict__ ls,     // (10,)
    const float* __restrict__ epsv,   // (10,)
    const int*   __restrict__ bidx,   // (2048,)
    const int*   __restrict__ nidx,   // (2048, 64)
    const float* __restrict__ tgt,    // (2048, 64, 10)
    float* __restrict__ out,          // pred | var | sigma
    float* __restrict__ ws)           // (M, BATCH) sigma contributions
{
    __shared__ float2 Ap[PPAD * NN];  // pair p, lane: {A[2p][lane], A[2p+1][lane]}

    const int b    = blockIdx.x;
    const int lane = threadIdx.x;

    // ---- lane's neighbor row -> 40 statically-indexed VGPRs ----
    const int nv = nidx[b * NN + lane];
    const float* xr0 = x + (size_t)nv * FEAT;
    float xc[FEAT];
#pragma unroll
    for (int q = 0; q < FEAT / 4; ++q) {
        const float4 v = *(const float4*)(xr0 + 4 * q);
        xc[4*q] = v.x; xc[4*q+1] = v.y; xc[4*q+2] = v.z; xc[4*q+3] = v.w;
    }
    float nl = 0.f;
#pragma unroll
    for (int f = 0; f < FEAT; ++f) nl = fmaf(xc[f], xc[f], nl);

    // ---- crosswise distance (batch row via uniform loads) ----
    const float* xbp = x + (size_t)bidx[b] * FEAT;
    float gc = 0.f, nb = 0.f;
#pragma unroll
    for (int f = 0; f < FEAT; ++f) {
        const float bf = xbp[f];
        gc = fmaf(bf, xc[f], gc);     // identical chains -> exact cancel on dup
        nb = fmaf(bf, bf, nb);
    }
    float cd2 = (nb + nl) - 2.f * gc;
    cd2 = (cd2 < 0.05f) ? 0.f : cd2;  // legit d2 ~ 80 in 40-D N(0,1) data
    const float cdv = sqrtf(cd2);

    unsigned done = 0;
    const unsigned all = (1u << M) - 1u;
    while (true) {
        const int   lead = __ffs(~done) - 1;     // wave-uniform
        const float lls  = ls[lead];
        const float lep  = epsv[lead];
        const float il   = -1.0f / lls;

        // ---- Gram + kernel transform, 2 rows/iter, unroll 2 ----
#pragma unroll 2
        for (int i = 0; i < NN; i += 2) {
            const int ri0 = rli(nv, i), ri1 = rli(nv, i + 1);
            const float* r0 = x + (size_t)ri0 * FEAT;   // uniform -> s_loads
            const float* r1 = x + (size_t)ri1 * FEAT;
            float g0 = 0.f, g1 = 0.f;
#pragma unroll
            for (int f = 0; f < FEAT; ++f) {
                g0 = fmaf(r0[f], xc[f], g0);
                g1 = fmaf(r1[f], xc[f], g1);
            }
            float d2a = (rl(g0, i) + nl) - 2.f * g0;    // Gram diag = |x_i|^2
            float d2b = (rl(g1, i + 1) + nl) - 2.f * g1;
            d2a = (d2a < 0.05f) ? 0.f : d2a;
            d2b = (d2b < 0.05f) ? 0.f : d2b;
            float va = __expf(sqrtf(d2a) * il);
            float vb = __expf(sqrtf(d2b) * il);
            if (lane == i)     va += lep;
            if (lane == i + 1) vb += lep;
            Ap[(i >> 1) * NN + lane] = float2{va, vb};  // ds_write_b64
        }
        const float kcv = __expf(cdv * il);

        // ---- RHS registers: z[0]=Kc, z[1..10]=targets ----
        float z[M + 1];
        z[0] = kcv;
        {
            const float* trow = tgt + ((size_t)b * NN + lane) * M;
#pragma unroll
            for (int q = 0; q < M / 2; ++q) {
                const float2 v = *(const float2*)(trow + 2 * q);
                z[2 * q + 1] = v.x; z[2 * q + 2] = v.y;
            }
        }

        // ---- fused rank-2 LDL^T + forward solves, float2 stream ----
        float2 pv = Ap[lane];             // pair 0 -> pivot rows 0,1
        float pc0 = pv.x, pc1 = pv.y;
        float2 nn2 = Ap[NN + lane];       // pair 1 -> next pivots
        float n2 = nn2.x, n3 = nn2.y;
        float rvv = 0.f;                  // this lane's 1/D[lane]
        for (int p = 0; p < 31; ++p) {
            const int k = 2 * p;
            // static prefetch: capture pair + first stream pair (pad-safe)
            const float2 V = Ap[(p + 2) * NN + lane];
            float2 U = Ap[(p + 3) * NN + lane];
            // pivot chain (register-only)
            const float d0  = rl(pc0, k);
            const float r0  = __builtin_amdgcn_rcpf(d0);
            const float cv0 = pc0 * (-r0);
            pc1 = fmaf(cv0, rl(pc0, k + 1), pc1);
            const float d1  = rl(pc1, k + 1);
            const float r1  = __builtin_amdgcn_rcpf(d1);
            const float cv1 = pc1 * (-r1);
            rvv = (lane == k)     ? r0 : rvv;
            rvv = (lane == k + 1) ? r1 : rvv;
            // fused solve updates for columns k, k+1
            const float lv0 = (lane > k)     ? cv0 : 0.f;
            const float lv1 = (lane > k + 1) ? cv1 : 0.f;
#pragma unroll
            for (int j = 0; j < M + 1; ++j) {
                z[j] = fmaf(lv0, rl(z[j], k), z[j]);
                z[j] = fmaf(lv1, rl(z[j], k + 1), z[j]);
            }
            // peel pair p+1 (registers) -> next pivots
            const float t2 = fmaf(cv1, rl(pc1, k + 2), fmaf(cv0, rl(pc0, k + 2), n2));
            const float t3 = fmaf(cv1, rl(pc1, k + 3), fmaf(cv0, rl(pc0, k + 3), n3));
            // capture pair p+2 in registers (never re-stored)
            n2 = fmaf(cv1, rl(pc1, k + 4), fmaf(cv0, rl(pc0, k + 4), V.x));
            n3 = fmaf(cv1, rl(pc1, k + 5), fmaf(cv0, rl(pc0, k + 5), V.y));
            // stream pairs p+3..31: one-ahead prefetched read/update/write
#pragma unroll 2
            for (int q = p + 3; q < NPAIR; ++q) {
                float2 cur = U;
                U = Ap[(q + 1) * NN + lane];             // pad-safe at q=31
                const int i0 = 2 * q;
                cur.x = fmaf(cv0, rl(pc0, i0),     fmaf(cv1, rl(pc1, i0),     cur.x));
                cur.y = fmaf(cv0, rl(pc0, i0 + 1), fmaf(cv1, rl(pc1, i0 + 1), cur.y));
                Ap[q * NN + lane] = cur;                 // ds_write_b64
            }
            pc0 = t2; pc1 = t3;
        }
        {   // final step k=62 (rows 62,63 in pc0,pc1)
            const float d0  = rl(pc0, 62);
            const float r0  = __builtin_amdgcn_rcpf(d0);
            const float cv0 = pc0 * (-r0);
            pc1 = fmaf(cv0, rl(pc0, 63), pc1);
            const float d1  = rl(pc1, 63);
            const float r1  = __builtin_amdgcn_rcpf(d1);
            rvv = (lane == 62) ? r0 : rvv;
            rvv = (lane == 63) ? r1 : rvv;
            const float lv0 = (lane > 62) ? cv0 : 0.f;   // col 63 affects nobody
#pragma unroll
            for (int j = 0; j < M + 1; ++j)
                z[j] = fmaf(lv0, rl(z[j], 62), z[j]);
        }

        // ---- quadratic forms with D^-1; lane-parallel output stores ----
        const float zc  = z[0];
        const float quad = wsum(zc * zc * rvv);
        unsigned mb = 0;
#pragma unroll
        for (int m = 0; m < M; ++m)
            if (!(done & (1u << m)) && ls[m] == lls && epsv[m] == lep)
                mb |= 1u << m;
        float predv = 0.f, sigv = 0.f;
#pragma unroll
        for (int m = 0; m < M; ++m) {
            if (mb & (1u << m)) {
                const float zm = z[m + 1];
                const float pm = wsum(zc * zm * rvv);
                const float sm = wsum(zm * zm * rvv);
                if (lane == m) { predv = pm; sigv = sm; }
            }
        }
        if (lane < M && ((mb >> lane) & 1u)) {
            out[b * M + lane] = predv;
            out[BATCH * M + b * M + lane] = 1.0f - quad;
            ws[lane * BATCH + b] = sigv;
        }
        done |= mb;
        if (done == all) break;
    }
}

// 1 block x 640: wave w reduces model w's 2048 contributions.
__global__ __launch_bounds__(640)
void sigma_reduce(const float* __restrict__ ws, float* __restrict__ out) {
    const int w = threadIdx.x >> 6, lane = threadIdx.x & 63;
    const float4* p = (const float4*)(ws + w * BATCH);
    float a = 0.f;
#pragma unroll
    for (int i = 0; i < BATCH / 4 / 64; ++i) {
        const float4 v = p[i * 64 + lane];
        a += (v.x + v.y) + (v.z + v.w);
    }
    a = wsum(a);
    if (lane == 0)
        out[2 * BATCH * M + w] = a * (1.0f / (float)(BATCH * NN));
}

extern "C" void kernel_launch(void* const* d_in, const int* in_sizes, int n_in,
                              void* d_out, int out_size, void* d_ws, size_t ws_size,
                              hipStream_t stream) {
    const float* x   = (const float*)d_in[0];
    const float* lsp = (const float*)d_in[1];
    const float* ep  = (const float*)d_in[2];
    const int*   bi  = (const int*)d_in[3];
    const int*   ni  = (const int*)d_in[4];
    const float* tg  = (const float*)d_in[5];
    float* out = (float*)d_out;
    float* ws  = (float*)d_ws;        // M*BATCH*4 = 80 KB

    muygps_kernel<<<BATCH, 64, 0, stream>>>(x, lsp, ep, bi, ni, tg, out, ws);
    sigma_reduce<<<1, 640, 0, stream>>>(ws, out);
}